// Round 5
// baseline (527.489 us; speedup 1.0000x reference)
//
#include <hip/hip_runtime.h>

// VQC: 18 qubits, 4 layers, batch 64.
// state[b][i], i = 18-bit index; qubit q <-> index bit (17-q).
// Layer = 18 one-qubit rotations (commuting) + CNOT chain == Gray permutation:
//   after_perm[o] = rotated[o ^ (o>>1)]   (folded into next phase-A load)
// Phase A: gates on index bits 0..8 (qubits 17..9), wave-local (regs + shfl).
// Phase B: gates on index bits 9..17 (qubits 8..0), LDS-transposed tile, in-place.
//   R3: 16 cols/block (full 128-B lines).  R5: persistent blocks, NT=8 tiles
//   each, double-buffered LDS (2x64 KiB) + reg-staged loads -> loads for t+1
//   in flight under compute of t (was serialized load-bar-compute-bar-store).
// Layer 0 on a basis input = outer product A_b[r]*B[c]; fused into first phase A.
// Final permutation + measurement folded into the last phase B (FINAL=1).
// State buffers are __device__ globals -> zero assumptions about ws_size.

#define NQ 18
#define NT 8
#define STATE_ELEMS ((size_t)1 << 24)  // 64 batches * 2^18

using cplx = float2;

__device__ cplx g_S[2][STATE_ELEMS];   // 2 x 128 MiB ping-pong
__device__ cplx g_Utab[4 * NQ * 4];
__device__ cplx g_Btab[512];

__device__ __forceinline__ cplx cmul(cplx a, cplx b) {
    return make_float2(a.x * b.x - a.y * b.y, a.x * b.y + a.y * b.x);
}
// a*o0 + b*o1 (complex)
__device__ __forceinline__ cplx cfma2(cplx a, cplx o0, cplx b, cplx o1) {
    float re = fmaf(a.x, o0.x, fmaf(-a.y, o0.y, fmaf(b.x, o1.x, -b.y * o1.y)));
    float im = fmaf(a.x, o0.y, fmaf(a.y, o0.x, fmaf(b.x, o1.y, b.y * o1.x)));
    return make_float2(re, im);
}

// ---------------------------------------------------------------- prep ------
// Utab[(l*18+q)*4 + row*2 + col]; Btab[c] = prod_j U[0][9+j][c_bit][0]
__global__ __launch_bounds__(512) void k_prep(const float* __restrict__ w) {
    __shared__ cplx Us[4 * NQ * 4];
    int tid = threadIdx.x;
    if (tid < 4 * NQ) {
        float phi = w[tid * 3 + 0], th = w[tid * 3 + 1], om = w[tid * 3 + 2];
        float s, c, sa, ca, sb, cb;
        sincosf(0.5f * th, &s, &c);
        sincosf(-0.5f * (phi + om), &sa, &ca);   // a = exp(-i(phi+om)/2)
        sincosf(0.5f * (phi - om), &sb, &cb);    // b = exp(+i(phi-om)/2)
        cplx U00 = make_float2(ca * c, sa * c);
        cplx U01 = make_float2(-cb * s, -sb * s);
        cplx U10 = make_float2(cb * s, -sb * s);  // conj(b)*s
        cplx U11 = make_float2(ca * c, -sa * c);  // conj(a)*c
        Us[tid * 4 + 0] = U00; Us[tid * 4 + 1] = U01;
        Us[tid * 4 + 2] = U10; Us[tid * 4 + 3] = U11;
        g_Utab[tid * 4 + 0] = U00; g_Utab[tid * 4 + 1] = U01;
        g_Utab[tid * 4 + 2] = U10; g_Utab[tid * 4 + 3] = U11;
    }
    __syncthreads();
    int c = tid;  // 0..511
    cplx B = make_float2(1.f, 0.f);
#pragma unroll
    for (int j = 0; j < 9; ++j) {
        int bit = (c >> (8 - j)) & 1;               // qubit 9+j = c bit (8-j)
        B = cmul(B, Us[(9 + j) * 4 + bit * 2 + 0]); // input bit 0
    }
    g_Btab[c] = B;
}

// ------------------------------------------------------------- gates --------
__device__ __forceinline__ void gate_inreg(cplx* T, int stride,
                                           cplx U00, cplx U01, cplx U10, cplx U11) {
#pragma unroll
    for (int t = 0; t < 8; ++t) {
        if ((t & stride) == 0) {
            cplx o0 = T[t], o1 = T[t | stride];
            T[t]          = cfma2(U00, o0, U01, o1);
            T[t | stride] = cfma2(U10, o0, U11, o1);
        }
    }
}
__device__ __forceinline__ void gate_shfl(cplx* T, int mask, int lanebit,
                                          cplx U00, cplx U01, cplx U10, cplx U11) {
    cplx ca = lanebit ? U11 : U00;
    cplx cb = lanebit ? U10 : U01;
#pragma unroll
    for (int t = 0; t < 8; ++t) {
        cplx p;
        p.x = __shfl_xor(T[t].x, mask);
        p.y = __shfl_xor(T[t].y, mask);
        T[t] = cfma2(ca, T[t], cb, p);
    }
}

#define GQ(q) UL[(q)*4+0], UL[(q)*4+1], UL[(q)*4+2], UL[(q)*4+3]

// ------------------------------------------------------------ phase A -------
// Per wave: output chunk h (512 elems) of batch b. Loads source chunk
// g = h^(h>>1) with the in-chunk Gray gather (per-lane 64B block, in-register
// unpermute), applies low-bit gates of `layer`, stores contiguous chunk h.
// GEN: source = A_b[g] * Btab[] (layer-0 output on basis state).
template <int GEN>
__global__ __launch_bounds__(256) void k_phaseA(int srcSel, int dstSel,
                                                const int* __restrict__ x,
                                                int layer) {
    const cplx* __restrict__ src = g_S[srcSel];
    cplx* __restrict__ dst = g_S[dstSel];
    const int lane = threadIdx.x & 63;
    const int W = blockIdx.x * 4 + (threadIdx.x >> 6);
    const int b = W >> 9;
    const int h = W & 511;
    const int g = h ^ (h >> 1);
    const int h0 = h & 1;
    const int blk = (lane ^ (lane >> 1)) ^ (h0 << 5);

    const float4* ls;
    if (GEN) ls = (const float4*)(g_Btab + blk * 8);
    else     ls = (const float4*)(src + (((size_t)b << 18) | (size_t)(g << 9)) + blk * 8);
    float4 q0 = ls[0], q1 = ls[1], q2 = ls[2], q3 = ls[3];
    cplx v[8] = { {q0.x,q0.y},{q0.z,q0.w},{q1.x,q1.y},{q1.z,q1.w},
                  {q2.x,q2.y},{q2.z,q2.w},{q3.x,q3.y},{q3.z,q3.w} };
    if (lane & 1) {  // in-block index ^= 4
#pragma unroll
        for (int j = 0; j < 4; ++j) { cplx t = v[j]; v[j] = v[j + 4]; v[j + 4] = t; }
    }
    // T[t] = v[gray3(t)]
    cplx T[8] = { v[0], v[1], v[3], v[2], v[6], v[7], v[5], v[4] };

    if (GEN) {
        cplx A = make_float2(1.f, 0.f);
#pragma unroll
        for (int j = 0; j < 9; ++j) {
            int bit = (g >> (8 - j)) & 1;  // qubit j = g bit (8-j)
            int xb = x[b * 9 + j];
            A = cmul(A, g_Utab[j * 4 + bit * 2 + xb]);
        }
#pragma unroll
        for (int t = 0; t < 8; ++t) T[t] = cmul(T[t], A);
    }

    const cplx* UL = g_Utab + layer * NQ * 4;
    gate_inreg(T, 1, GQ(17));   // index bit 0
    gate_inreg(T, 2, GQ(16));   // index bit 1
    gate_inreg(T, 4, GQ(15));   // index bit 2
    gate_shfl(T, 1,  lane & 1,  GQ(14));  // index bit 3
    gate_shfl(T, 2,  lane & 2,  GQ(13));
    gate_shfl(T, 4,  lane & 4,  GQ(12));
    gate_shfl(T, 8,  lane & 8,  GQ(11));
    gate_shfl(T, 16, lane & 16, GQ(10));
    gate_shfl(T, 32, lane & 32, GQ(9));   // index bit 8

    float4* ld = (float4*)(dst + (((size_t)b << 18) | (size_t)(h << 9)) + lane * 8);
    ld[0] = make_float4(T[0].x, T[0].y, T[1].x, T[1].y);
    ld[1] = make_float4(T[2].x, T[2].y, T[3].x, T[3].y);
    ld[2] = make_float4(T[4].x, T[4].y, T[5].x, T[5].y);
    ld[3] = make_float4(T[6].x, T[6].y, T[7].x, T[7].y);
}

// ------------------------------------------------------------ phase B -------
// In-place, persistent-pipelined. Block: 1024 threads, NT=8 consecutive tiles
// (tile = batch b x 16 columns, all 512 rows). Double-buffered 64-KiB LDS
// tiles; next tile's global loads issued before compute of current tile so
// HBM latency hides under the gates; stores overlap the next iteration.
// LDS col-major with 16B-unit XOR swizzle (u' = u ^ ((u>>3)&7)).
// Wave wv (0..15) owns column wv: 8 rows/lane in registers.
// FINAL: no writeback/stores; accumulate signed |amp|^2 across tiles
// (final Gray perm -> sign bits are per-lane constants: lane bits 5..2).
template <int FINAL>
__global__ __launch_bounds__(1024) void k_phaseB(int sel, int layer,
                                                 float* __restrict__ out) {
    cplx* __restrict__ state = g_S[sel];
    __shared__ cplx buf[2][16 * 512];  // 128 KiB
    __shared__ float facc[16][4];
    const int tid = threadIdx.x;
    const int lane = tid & 63;
    const int wv = tid >> 6;                   // 0..15
    const int r = tid >> 1, half = tid & 1;    // stage row / line-half
    const int u_st = r >> 1;
    const int us_st = u_st ^ ((u_st >> 3) & 7);
    const int basep = us_st * 2 + (r & 1);
    const int tile0 = blockIdx.x * NT;
    const int b = tile0 >> 5;                  // constant per block (8 | 32)
    const int cb0 = tile0 & 31;
    const cplx* UL = g_Utab + layer * NQ * 4;

    // this thread's staged 64-B segment of tile t is at gthr + t*16
    cplx* gthr = state + (((size_t)b << 18) | (size_t)(cb0 * 16))
                       + ((size_t)r << 9) + half * 8;

    float4 a0, a1, a2, a3;
    { const float4* gs = (const float4*)gthr;
      a0 = gs[0]; a1 = gs[1]; a2 = gs[2]; a3 = gs[3]; }

    float e0 = 0.f, e1 = 0.f, e2 = 0.f, e3 = 0.f;

#pragma unroll
    for (int t = 0; t < NT; ++t) {
        cplx* __restrict__ B = buf[t & 1];
        {   // stage-in from regs (vmcnt wait inserted by compiler)
            cplx w8[8] = { {a0.x,a0.y},{a0.z,a0.w},{a1.x,a1.y},{a1.z,a1.w},
                           {a2.x,a2.y},{a2.z,a2.w},{a3.x,a3.y},{a3.z,a3.w} };
#pragma unroll
            for (int k = 0; k < 8; ++k) B[(half * 8 + k) * 512 + basep] = w8[k];
        }
        if (t + 1 < NT) {  // issue next tile's loads; in flight under compute
            const float4* gs = (const float4*)(gthr + (t + 1) * 16);
            a0 = gs[0]; a1 = gs[1]; a2 = gs[2]; a3 = gs[3];
        }
        __syncthreads();

        cplx T[8];  // rows lane*8 .. lane*8+7 of column wv
#pragma unroll
        for (int j = 0; j < 4; ++j) {
            int u = lane * 4 + j;
            int us = u ^ ((u >> 3) & 7);
            float4 q = *(const float4*)&B[wv * 512 + us * 2];
            T[2 * j]     = make_float2(q.x, q.y);
            T[2 * j + 1] = make_float2(q.z, q.w);
        }

        gate_inreg(T, 1, GQ(8));    // index bit 9
        gate_inreg(T, 2, GQ(7));
        gate_inreg(T, 4, GQ(6));
        gate_shfl(T, 1,  lane & 1,  GQ(5));  // index bit 12
        gate_shfl(T, 2,  lane & 2,  GQ(4));
        gate_shfl(T, 4,  lane & 4,  GQ(3));
        gate_shfl(T, 8,  lane & 8,  GQ(2));
        gate_shfl(T, 16, lane & 16, GQ(1));
        gate_shfl(T, 32, lane & 32, GQ(0));  // index bit 17

        if (FINAL) {
            float s = 0.f;
#pragma unroll
            for (int k = 0; k < 8; ++k)
                s = fmaf(T[k].x, T[k].x, fmaf(T[k].y, T[k].y, s));
            // final perm: o = invGray(m); sign = prefix parity of m bits 17..14
            int l5 = (lane >> 5) & 1, l4 = (lane >> 4) & 1;
            int l3 = (lane >> 3) & 1, l2 = (lane >> 2) & 1;
            int o17 = l5, o16 = o17 ^ l4, o15 = o16 ^ l3, o14 = o15 ^ l2;
            e0 += o17 ? -s : s; e1 += o16 ? -s : s;
            e2 += o15 ? -s : s; e3 += o14 ? -s : s;
            // next iter's stage-in targets the other buffer; safe past this
            // iter's barrier (fragment reads of buf[(t+1)&1] were pre-bar(t)).
        } else {
#pragma unroll
            for (int j = 0; j < 4; ++j) {  // writeback own column (no hazard)
                int u = lane * 4 + j;
                int us = u ^ ((u >> 3) & 7);
                *(float4*)&B[wv * 512 + us * 2] =
                    make_float4(T[2 * j].x, T[2 * j].y,
                                T[2 * j + 1].x, T[2 * j + 1].y);
            }
            __syncthreads();
            {   // stage-out; stores overlap next iteration
                cplx o[8];
#pragma unroll
                for (int k = 0; k < 8; ++k) o[k] = B[(half * 8 + k) * 512 + basep];
                float4* gd = (float4*)(gthr + t * 16);
                gd[0] = make_float4(o[0].x, o[0].y, o[1].x, o[1].y);
                gd[1] = make_float4(o[2].x, o[2].y, o[3].x, o[3].y);
                gd[2] = make_float4(o[4].x, o[4].y, o[5].x, o[5].y);
                gd[3] = make_float4(o[6].x, o[6].y, o[7].x, o[7].y);
            }
        }
    }

    if (FINAL) {
#pragma unroll
        for (int off = 32; off >= 1; off >>= 1) {
            e0 += __shfl_xor(e0, off); e1 += __shfl_xor(e1, off);
            e2 += __shfl_xor(e2, off); e3 += __shfl_xor(e3, off);
        }
        if (lane == 0) {
            facc[wv][0] = e0; facc[wv][1] = e1;
            facc[wv][2] = e2; facc[wv][3] = e3;
        }
        __syncthreads();
        if (tid < 4) {
            float tot = 0.f;
#pragma unroll
            for (int k = 0; k < 16; ++k) tot += facc[k][tid];
            atomicAdd(&out[b * 4 + tid], tot);
        }
    }
}

// ------------------------------------------------------------- launch -------
extern "C" void kernel_launch(void* const* d_in, const int* in_sizes, int n_in,
                              void* d_out, int out_size, void* d_ws, size_t ws_size,
                              hipStream_t stream) {
    const float* w = (const float*)d_in[0];   // (4,18,3) f32
    const int* x = (const int*)d_in[1];       // (64,9) i32
    float* out = (float*)d_out;               // (64,4) f32
    (void)d_ws; (void)ws_size; (void)n_in; (void)in_sizes;

    hipMemsetAsync(d_out, 0, (size_t)out_size * sizeof(float), stream);
    k_prep<<<1, 512, 0, stream>>>(w);
    // layer 0 (A*B outer product) + perm + layer-1 low gates -> S0
    k_phaseA<1><<<8192, 256, 0, stream>>>(0, 0, x, 1);
    k_phaseB<0><<<256, 1024, 0, stream>>>(0, 1, nullptr);   // layer-1 high gates
    k_phaseA<0><<<8192, 256, 0, stream>>>(0, 1, x, 2);
    k_phaseB<0><<<256, 1024, 0, stream>>>(1, 2, nullptr);
    k_phaseA<0><<<8192, 256, 0, stream>>>(1, 0, x, 3);
    // layer-3 high gates + final perm + measurement (no writeback)
    k_phaseB<1><<<256, 1024, 0, stream>>>(0, 3, out);
}

// Round 6
// 473.984 us; speedup vs baseline: 1.1129x; 1.1129x over previous
//
#include <hip/hip_runtime.h>

// VQC: 18 qubits, 4 layers, batch 64.
// state[b][i], i = 18-bit index; qubit q <-> index bit (17-q).
// Layer = 18 one-qubit rotations (commuting) + CNOT chain == Gray permutation:
//   after_perm[o] = rotated[o ^ (o>>1)]   (folded into next phase-A load)
// Phase A: gates on index bits 0..8 AND bit 17 (qubits 17..9 + qubit 0).
//   Wave handles out-chunk pair (h, h|256): T[16]; bit-17 gate = stride-8 pairs.
// Phase B: gates on index bits 9..16 (qubits 8..1), 256-row LDS tile, in-place.
//   R6: 32-KiB tiles + 512-thr blocks -> 4 blocks/CU (was 64 KiB/2 blocks; R5's
//   persistent pipeline caused 2.4x write amplification - reverted).
// Layer 0 on a basis input = outer product A_b[r]*B[c]; fused into first phase A.
// Final permutation + measurement folded into the last phase B (FINAL=1):
//   m bits 17..14 = (H, lane5, lane4, lane3) -> signs are per-lane constants.
// State buffers are __device__ globals -> zero assumptions about ws_size.

#define NQ 18
#define STATE_ELEMS ((size_t)1 << 24)  // 64 batches * 2^18

using cplx = float2;

__device__ cplx g_S[2][STATE_ELEMS];   // 2 x 128 MiB ping-pong
__device__ cplx g_Utab[4 * NQ * 4];
__device__ cplx g_Btab[512];

__device__ __forceinline__ cplx cmul(cplx a, cplx b) {
    return make_float2(a.x * b.x - a.y * b.y, a.x * b.y + a.y * b.x);
}
// a*o0 + b*o1 (complex)
__device__ __forceinline__ cplx cfma2(cplx a, cplx o0, cplx b, cplx o1) {
    float re = fmaf(a.x, o0.x, fmaf(-a.y, o0.y, fmaf(b.x, o1.x, -b.y * o1.y)));
    float im = fmaf(a.x, o0.y, fmaf(a.y, o0.x, fmaf(b.x, o1.y, b.y * o1.x)));
    return make_float2(re, im);
}

// ---------------------------------------------------------------- prep ------
// Utab[(l*18+q)*4 + row*2 + col]; Btab[c] = prod_j U[0][9+j][c_bit][0]
__global__ __launch_bounds__(512) void k_prep(const float* __restrict__ w) {
    __shared__ cplx Us[4 * NQ * 4];
    int tid = threadIdx.x;
    if (tid < 4 * NQ) {
        float phi = w[tid * 3 + 0], th = w[tid * 3 + 1], om = w[tid * 3 + 2];
        float s, c, sa, ca, sb, cb;
        sincosf(0.5f * th, &s, &c);
        sincosf(-0.5f * (phi + om), &sa, &ca);   // a = exp(-i(phi+om)/2)
        sincosf(0.5f * (phi - om), &sb, &cb);    // b = exp(+i(phi-om)/2)
        cplx U00 = make_float2(ca * c, sa * c);
        cplx U01 = make_float2(-cb * s, -sb * s);
        cplx U10 = make_float2(cb * s, -sb * s);  // conj(b)*s
        cplx U11 = make_float2(ca * c, -sa * c);  // conj(a)*c
        Us[tid * 4 + 0] = U00; Us[tid * 4 + 1] = U01;
        Us[tid * 4 + 2] = U10; Us[tid * 4 + 3] = U11;
        g_Utab[tid * 4 + 0] = U00; g_Utab[tid * 4 + 1] = U01;
        g_Utab[tid * 4 + 2] = U10; g_Utab[tid * 4 + 3] = U11;
    }
    __syncthreads();
    int c = tid;  // 0..511
    cplx B = make_float2(1.f, 0.f);
#pragma unroll
    for (int j = 0; j < 9; ++j) {
        int bit = (c >> (8 - j)) & 1;               // qubit 9+j = c bit (8-j)
        B = cmul(B, Us[(9 + j) * 4 + bit * 2 + 0]); // input bit 0
    }
    g_Btab[c] = B;
}

// ------------------------------------------------------------- gates --------
template <int N>
__device__ __forceinline__ void gate_inreg(cplx* T, int stride,
                                           cplx U00, cplx U01, cplx U10, cplx U11) {
#pragma unroll
    for (int t = 0; t < N; ++t) {
        if ((t & stride) == 0) {
            cplx o0 = T[t], o1 = T[t | stride];
            T[t]          = cfma2(U00, o0, U01, o1);
            T[t | stride] = cfma2(U10, o0, U11, o1);
        }
    }
}
template <int N>
__device__ __forceinline__ void gate_shfl(cplx* T, int mask, int lanebit,
                                          cplx U00, cplx U01, cplx U10, cplx U11) {
    cplx ca = lanebit ? U11 : U00;
    cplx cb = lanebit ? U10 : U01;
#pragma unroll
    for (int t = 0; t < N; ++t) {
        cplx p;
        p.x = __shfl_xor(T[t].x, mask);
        p.y = __shfl_xor(T[t].y, mask);
        T[t] = cfma2(ca, T[t], cb, p);
    }
}

#define GQ(q) UL[(q)*4+0], UL[(q)*4+1], UL[(q)*4+2], UL[(q)*4+3]

// ------------------------------------------------------------ phase A -------
// Per wave: output chunk PAIR (hl, hl|256) of batch b (chunk = 512 elems).
// Loads source chunks g0 = hl^(hl>>1) and g1 = (g0^0x80)|0x100 with the
// in-chunk Gray gather (per-lane 64B block, in-register unpermute), applies
// gates for index bits 0..8 (qubits 17..9) and bit 17 (qubit 0, stride-8
// in-register pairs), stores contiguous chunks hl and hl|256.
// GEN: source = A_b[g] * Btab[] (layer-0 output on basis state).
template <int GEN>
__global__ __launch_bounds__(256) void k_phaseA(int srcSel, int dstSel,
                                                const int* __restrict__ x,
                                                int layer) {
    const cplx* __restrict__ src = g_S[srcSel];
    cplx* __restrict__ dst = g_S[dstSel];
    const int lane = threadIdx.x & 63;
    const int W = blockIdx.x * 4 + (threadIdx.x >> 6);
    const int b = W >> 8;
    const int hl = W & 255;                    // out chunks hl, hl|256
    const int g0 = hl ^ (hl >> 1);
    const int g1 = (g0 ^ 0x80) | 0x100;
    const int h0 = hl & 1;
    const int blk = (lane ^ (lane >> 1)) ^ (h0 << 5);

    cplx T[16];
#pragma unroll
    for (int cpair = 0; cpair < 2; ++cpair) {
        const int g = cpair ? g1 : g0;
        const float4* ls;
        if (GEN) ls = (const float4*)(g_Btab + blk * 8);
        else     ls = (const float4*)(src + (((size_t)b << 18) | (size_t)(g << 9)) + blk * 8);
        float4 q0 = ls[0], q1 = ls[1], q2 = ls[2], q3 = ls[3];
        cplx v[8] = { {q0.x,q0.y},{q0.z,q0.w},{q1.x,q1.y},{q1.z,q1.w},
                      {q2.x,q2.y},{q2.z,q2.w},{q3.x,q3.y},{q3.z,q3.w} };
        if (lane & 1) {  // in-block index ^= 4
#pragma unroll
            for (int j = 0; j < 4; ++j) { cplx t = v[j]; v[j] = v[j + 4]; v[j + 4] = t; }
        }
        // T[t] = v[gray3(t)]
        cplx* Tc = T + cpair * 8;
        Tc[0] = v[0]; Tc[1] = v[1]; Tc[2] = v[3]; Tc[3] = v[2];
        Tc[4] = v[6]; Tc[5] = v[7]; Tc[6] = v[5]; Tc[7] = v[4];

        if (GEN) {
            cplx A = make_float2(1.f, 0.f);
#pragma unroll
            for (int j = 0; j < 9; ++j) {
                int bit = (g >> (8 - j)) & 1;  // qubit j = g bit (8-j)
                int xb = x[b * 9 + j];
                A = cmul(A, g_Utab[j * 4 + bit * 2 + xb]);
            }
#pragma unroll
            for (int t = 0; t < 8; ++t) Tc[t] = cmul(Tc[t], A);
        }
    }

    const cplx* UL = g_Utab + layer * NQ * 4;
    gate_inreg<16>(T, 1, GQ(17));   // index bit 0
    gate_inreg<16>(T, 2, GQ(16));   // index bit 1
    gate_inreg<16>(T, 4, GQ(15));   // index bit 2
    gate_shfl<16>(T, 1,  lane & 1,  GQ(14));  // index bit 3
    gate_shfl<16>(T, 2,  lane & 2,  GQ(13));
    gate_shfl<16>(T, 4,  lane & 4,  GQ(12));
    gate_shfl<16>(T, 8,  lane & 8,  GQ(11));
    gate_shfl<16>(T, 16, lane & 16, GQ(10));
    gate_shfl<16>(T, 32, lane & 32, GQ(9));   // index bit 8
    gate_inreg<16>(T, 8, GQ(0));    // index bit 17 (qubit 0): pairs (t, t+8)

#pragma unroll
    for (int cpair = 0; cpair < 2; ++cpair) {
        const int h = hl | (cpair << 8);
        const cplx* Tc = T + cpair * 8;
        float4* ld = (float4*)(dst + (((size_t)b << 18) | (size_t)(h << 9)) + lane * 8);
        ld[0] = make_float4(Tc[0].x, Tc[0].y, Tc[1].x, Tc[1].y);
        ld[1] = make_float4(Tc[2].x, Tc[2].y, Tc[3].x, Tc[3].y);
        ld[2] = make_float4(Tc[4].x, Tc[4].y, Tc[5].x, Tc[5].y);
        ld[3] = make_float4(Tc[6].x, Tc[6].y, Tc[7].x, Tc[7].y);
    }
}

// ------------------------------------------------------------ phase B -------
// In-place. Block: 512 threads; tile = batch b, row-half H (256 rows),
// 16 columns. Stage-in/out: thread pair (2m,2m+1) covers one full 128-B line.
// LDS col-major, 16-B-unit XOR swizzle (u' = u ^ ((u>>3)&7)) -> spread banks.
// Wave wv (0..7) owns cols 2wv, 2wv+1: T[8] = {col0 rows j0..3, col1 j0..3},
// row(within half) = lane*4 + j. Gates: bits 9,10 in-reg (stride 1,2);
// bits 11..16 shfl (masks 1..32). 32-KiB tile -> 4 blocks/CU.
// FINAL: fold final Gray perm + measurement: m bits 17..14 = (H,l5,l4,l3).
template <int FINAL>
__global__ __launch_bounds__(512) void k_phaseB(int sel, int layer,
                                                float* __restrict__ out) {
    cplx* __restrict__ state = g_S[sel];
    __shared__ cplx tile[16 * 256];  // 32 KiB
    __shared__ float facc[8][4];
    const int tid = threadIdx.x;
    const int lane = tid & 63;
    const int wv = tid >> 6;                 // 0..7
    const int b = blockIdx.x >> 6;
    const int H = (blockIdx.x >> 5) & 1;     // row half (index bit 17)
    const int cb = blockIdx.x & 31;          // column block (16 cols)
    cplx* gbase = state + (((size_t)b << 18) | ((size_t)H << 17) | (size_t)(cb * 16));

    {   // stage in: r = tid>>1 (0..255), half = tid&1 -> 8 cols (64 B)
        const int r = tid >> 1, half = tid & 1;
        const float4* gs = (const float4*)(gbase + ((size_t)r << 9) + half * 8);
        float4 a0 = gs[0], a1 = gs[1], a2 = gs[2], a3 = gs[3];
        cplx w8[8] = { {a0.x,a0.y},{a0.z,a0.w},{a1.x,a1.y},{a1.z,a1.w},
                       {a2.x,a2.y},{a2.z,a2.w},{a3.x,a3.y},{a3.z,a3.w} };
        int u = r >> 1;
        int us = u ^ ((u >> 3) & 7);
        int basep = us * 2 + (r & 1);
#pragma unroll
        for (int k = 0; k < 8; ++k) tile[(half * 8 + k) * 256 + basep] = w8[k];
    }
    __syncthreads();

    cplx T[8];  // cols 2wv, 2wv+1; rows lane*4 .. lane*4+3 (within half)
#pragma unroll
    for (int cc = 0; cc < 2; ++cc) {
        const int col = wv * 2 + cc;
#pragma unroll
        for (int uu = 0; uu < 2; ++uu) {
            int u = lane * 2 + uu;
            int us = u ^ ((u >> 3) & 7);
            float4 q = *(const float4*)&tile[col * 256 + us * 2];
            T[cc * 4 + uu * 2]     = make_float2(q.x, q.y);
            T[cc * 4 + uu * 2 + 1] = make_float2(q.z, q.w);
        }
    }

    const cplx* UL = g_Utab + layer * NQ * 4;
    gate_inreg<8>(T, 1, GQ(8));    // index bit 9
    gate_inreg<8>(T, 2, GQ(7));    // index bit 10
    gate_shfl<8>(T, 1,  lane & 1,  GQ(6));  // index bit 11
    gate_shfl<8>(T, 2,  lane & 2,  GQ(5));
    gate_shfl<8>(T, 4,  lane & 4,  GQ(4));
    gate_shfl<8>(T, 8,  lane & 8,  GQ(3));
    gate_shfl<8>(T, 16, lane & 16, GQ(2));
    gate_shfl<8>(T, 32, lane & 32, GQ(1));  // index bit 16

    if (FINAL) {
        float s = 0.f;
#pragma unroll
        for (int t = 0; t < 8; ++t)
            s = fmaf(T[t].x, T[t].x, fmaf(T[t].y, T[t].y, s));
        // final perm: o = invGray(m); sign bits = prefix parity of m bits 17..14
        // m17..14 = (H, lane5, lane4, lane3)
        int l5 = (lane >> 5) & 1, l4 = (lane >> 4) & 1, l3 = (lane >> 3) & 1;
        int o17 = H, o16 = o17 ^ l5, o15 = o16 ^ l4, o14 = o15 ^ l3;
        float e0 = o17 ? -s : s, e1 = o16 ? -s : s;
        float e2 = o15 ? -s : s, e3 = o14 ? -s : s;
#pragma unroll
        for (int off = 32; off >= 1; off >>= 1) {
            e0 += __shfl_xor(e0, off); e1 += __shfl_xor(e1, off);
            e2 += __shfl_xor(e2, off); e3 += __shfl_xor(e3, off);
        }
        if (lane == 0) {
            facc[wv][0] = e0; facc[wv][1] = e1;
            facc[wv][2] = e2; facc[wv][3] = e3;
        }
        __syncthreads();
        if (tid < 4) {
            float tot = 0.f;
#pragma unroll
            for (int k = 0; k < 8; ++k) tot += facc[k][tid];
            atomicAdd(&out[b * 4 + tid], tot);
        }
        return;
    }

#pragma unroll
    for (int cc = 0; cc < 2; ++cc) {   // writeback own cols (no cross-wave hazard)
        const int col = wv * 2 + cc;
#pragma unroll
        for (int uu = 0; uu < 2; ++uu) {
            int u = lane * 2 + uu;
            int us = u ^ ((u >> 3) & 7);
            *(float4*)&tile[col * 256 + us * 2] =
                make_float4(T[cc * 4 + uu * 2].x,     T[cc * 4 + uu * 2].y,
                            T[cc * 4 + uu * 2 + 1].x, T[cc * 4 + uu * 2 + 1].y);
        }
    }
    __syncthreads();

    {   // stage out
        const int r = tid >> 1, half = tid & 1;
        int u = r >> 1;
        int us = u ^ ((u >> 3) & 7);
        int basep = us * 2 + (r & 1);
        cplx o[8];
#pragma unroll
        for (int k = 0; k < 8; ++k) o[k] = tile[(half * 8 + k) * 256 + basep];
        float4* gd = (float4*)(gbase + ((size_t)r << 9) + half * 8);
        gd[0] = make_float4(o[0].x, o[0].y, o[1].x, o[1].y);
        gd[1] = make_float4(o[2].x, o[2].y, o[3].x, o[3].y);
        gd[2] = make_float4(o[4].x, o[4].y, o[5].x, o[5].y);
        gd[3] = make_float4(o[6].x, o[6].y, o[7].x, o[7].y);
    }
}

// ------------------------------------------------------------- launch -------
extern "C" void kernel_launch(void* const* d_in, const int* in_sizes, int n_in,
                              void* d_out, int out_size, void* d_ws, size_t ws_size,
                              hipStream_t stream) {
    const float* w = (const float*)d_in[0];   // (4,18,3) f32
    const int* x = (const int*)d_in[1];       // (64,9) i32
    float* out = (float*)d_out;               // (64,4) f32
    (void)d_ws; (void)ws_size; (void)n_in; (void)in_sizes;

    hipMemsetAsync(d_out, 0, (size_t)out_size * sizeof(float), stream);
    k_prep<<<1, 512, 0, stream>>>(w);
    // layer 0 (A*B outer product) + perm + layer-1 low gates + bit17 -> S0
    k_phaseA<1><<<4096, 256, 0, stream>>>(0, 0, x, 1);
    k_phaseB<0><<<4096, 512, 0, stream>>>(0, 1, nullptr);   // layer-1 bits 9..16
    k_phaseA<0><<<4096, 256, 0, stream>>>(0, 1, x, 2);
    k_phaseB<0><<<4096, 512, 0, stream>>>(1, 2, nullptr);
    k_phaseA<0><<<4096, 256, 0, stream>>>(1, 0, x, 3);
    // layer-3 bits 9..16 + final perm + measurement (no writeback)
    k_phaseB<1><<<4096, 512, 0, stream>>>(0, 3, out);
}

// Round 7
// 114.490 us; speedup vs baseline: 4.6073x; 4.1400x over previous
//
#include <hip/hip_runtime.h>

// VQC: 18 qubits, 4 layers, batch 64 — FACTORIZED (no 2^18 state).
// Across the row/col cut (index bits 9..17 | 0..8) only one CNOT per layer
// crosses (the g_8 = o_8 ^ o_9 term of the Gray perm o -> o^(o>>1)), so the
// state is always  sum_k E_k[R] * C_k[C]  with rank doubling per layer:
// 1->2->4->8->16.  Col vectors are batch-independent; row vectors carry x_b.
//   perm: E'_{2k+q}[R] = (R&1==q) ? E_k[R^(R>>1)] : 0
//         C'_{2k+q}[C] = C_k[(C^(C>>1)) ^ (q<<8)]
// Measurement: ev_i(b) = sum_R s_i[R] * M[R],
//   M[R] = sum_{k,k'} E_k[R] conj(E_k'[R]) G[k,k'],  G = col Gram (16x16),
//   s_i = sign from R bit (8-i)  (post-final-perm index, bits 17..14 = R 8..5).
// k_prep: Utab + col pipeline + Gram (1 block). k_row: 64 blocks (1/batch).

#define NQ 18

using cplx = float2;

__device__ cplx g_Utab[4 * NQ * 4];
__device__ cplx g_G[256];   // col Gram, 16x16 complex

__device__ __forceinline__ cplx cmul(cplx a, cplx b) {
    return make_float2(a.x * b.x - a.y * b.y, a.x * b.y + a.y * b.x);
}
// a*o0 + b*o1 (complex)
__device__ __forceinline__ cplx cfma2(cplx a, cplx o0, cplx b, cplx o1) {
    float re = fmaf(a.x, o0.x, fmaf(-a.y, o0.y, fmaf(b.x, o1.x, -b.y * o1.y)));
    float im = fmaf(a.x, o0.y, fmaf(a.y, o0.x, fmaf(b.x, o1.y, b.y * o1.x)));
    return make_float2(re, im);
}

// Apply layer-l single-qubit gates to K vectors in LDS (in place).
// idx = this thread's element (0..511). Gate on bit bpos pairs idx, idx^m.
// qof: qubit = qof - bpos  (row side qof=8, col side qof=17).
template <int K>
__device__ __forceinline__ void apply_gates(cplx (*buf)[512], const cplx* Us,
                                            int l, int qof, int idx) {
    for (int bpos = 0; bpos < 9; ++bpos) {
        const int m = 1 << bpos;
        const int bit = (idx >> bpos) & 1;
        const int p = idx ^ m;
        const cplx* U = &Us[(l * NQ + (qof - bpos)) * 4];
        const cplx ua = bit ? U[3] : U[0];   // U[new=bit][old=bit]
        const cplx ub = bit ? U[2] : U[1];   // U[new=bit][old=bit^1]
        cplx mine[K], part[K];
#pragma unroll
        for (int k = 0; k < K; ++k) { mine[k] = buf[k][idx]; part[k] = buf[k][p]; }
        __syncthreads();
#pragma unroll
        for (int k = 0; k < K; ++k) buf[k][idx] = cfma2(ua, mine[k], ub, part[k]);
        __syncthreads();
    }
}

// Gray perm + rank split, in place. k descending: step k reads row k, writes
// rows 2k,2k+1 — never clobbers a not-yet-read row (2k > k-1).
template <int K, int ROW>
__device__ __forceinline__ void apply_perm(cplx (*buf)[512], int idx) {
    const int gi = idx ^ (idx >> 1);
#pragma unroll
    for (int k = K - 1; k >= 0; --k) {
        cplx v0, v1;
        if (ROW) {
            cplx v = buf[k][gi];
            v0 = (idx & 1) ? make_float2(0.f, 0.f) : v;
            v1 = (idx & 1) ? v : make_float2(0.f, 0.f);
        } else {
            v0 = buf[k][gi];
            v1 = buf[k][gi ^ 256];
        }
        __syncthreads();
        buf[2 * k][idx] = v0;
        buf[2 * k + 1][idx] = v1;
        __syncthreads();
    }
}

// ---------------------------------------------------------------- prep ------
// Utab -> global; col pipeline (batch-independent, input col = 0) -> Gram.
__global__ __launch_bounds__(512) void k_prep(const float* __restrict__ w) {
    __shared__ cplx Us[4 * NQ * 4];
    __shared__ cplx cbuf[16][512];   // 64 KiB
    const int tid = threadIdx.x;
    if (tid < 4 * NQ) {
        float phi = w[tid * 3 + 0], th = w[tid * 3 + 1], om = w[tid * 3 + 2];
        float s, c, sa, ca, sb, cb;
        sincosf(0.5f * th, &s, &c);
        sincosf(-0.5f * (phi + om), &sa, &ca);   // a = exp(-i(phi+om)/2)
        sincosf(0.5f * (phi - om), &sb, &cb);    // b = exp(+i(phi-om)/2)
        cplx U00 = make_float2(ca * c, sa * c);
        cplx U01 = make_float2(-cb * s, -sb * s);
        cplx U10 = make_float2(cb * s, -sb * s);  // conj(b)*s
        cplx U11 = make_float2(ca * c, -sa * c);  // conj(a)*c
        Us[tid * 4 + 0] = U00; Us[tid * 4 + 1] = U01;
        Us[tid * 4 + 2] = U10; Us[tid * 4 + 3] = U11;
        g_Utab[tid * 4 + 0] = U00; g_Utab[tid * 4 + 1] = U01;
        g_Utab[tid * 4 + 2] = U10; g_Utab[tid * 4 + 3] = U11;
    }
    __syncthreads();
    const int c = tid;   // col index 0..511
    {   // layer-0 low gates on basis col 0: product form (old Btab)
        cplx B = make_float2(1.f, 0.f);
#pragma unroll
        for (int j = 0; j < 9; ++j) {
            int bit = (c >> (8 - j)) & 1;               // qubit 9+j = col bit 8-j
            B = cmul(B, Us[(9 + j) * 4 + bit * 2 + 0]); // input bit 0
        }
        cbuf[0][c] = B;
    }
    __syncthreads();
    apply_perm<1, 0>(cbuf, c);
    apply_gates<2>(cbuf, Us, 1, 17, c);
    apply_perm<2, 0>(cbuf, c);
    apply_gates<4>(cbuf, Us, 2, 17, c);
    apply_perm<4, 0>(cbuf, c);
    apply_gates<8>(cbuf, Us, 3, 17, c);
    apply_perm<8, 0>(cbuf, c);
    // Gram: G[k,k'] = sum_C C_k[C] * conj(C_k'[C])
    if (tid < 256) {
        const int k = tid >> 4, k2 = tid & 15;
        float gr = 0.f, gi = 0.f;
        for (int cc = 0; cc < 512; ++cc) {
            cplx a = cbuf[k][cc], b = cbuf[k2][cc];
            gr = fmaf(a.x, b.x, fmaf(a.y, b.y, gr));
            gi = fmaf(a.y, b.x, fmaf(-a.x, b.y, gi));
        }
        g_G[tid] = make_float2(gr, gi);
    }
}

// ----------------------------------------------------------------- row ------
// One block per batch. Row pipeline in LDS, then M[R] via Gram, signed sums.
__global__ __launch_bounds__(512) void k_row(const int* __restrict__ x,
                                             float* __restrict__ out) {
    __shared__ cplx Us[4 * NQ * 4];
    __shared__ cplx rbuf[16][512];   // 64 KiB
    __shared__ cplx Gs[256];
    __shared__ float red[8][4];
    const int tid = threadIdx.x;
    const int b = blockIdx.x;
    if (tid < 4 * NQ * 4) Us[tid] = g_Utab[tid];
    if (tid < 256) Gs[tid] = g_G[tid];
    const int r = tid;   // row index 0..511
    cplx A = make_float2(1.f, 0.f);
#pragma unroll
    for (int j = 0; j < 9; ++j) {   // layer-0 high gates on basis row (closed form)
        int bit = (r >> (8 - j)) & 1;   // qubit j = row bit 8-j
        int xb = x[b * 9 + j];
        A = cmul(A, g_Utab[j * 4 + bit * 2 + xb]);
    }
    __syncthreads();
    rbuf[0][r] = A;
    __syncthreads();
    apply_perm<1, 1>(rbuf, r);
    apply_gates<2>(rbuf, Us, 1, 8, r);
    apply_perm<2, 1>(rbuf, r);
    apply_gates<4>(rbuf, Us, 2, 8, r);
    apply_perm<4, 1>(rbuf, r);
    apply_gates<8>(rbuf, Us, 3, 8, r);
    apply_perm<8, 1>(rbuf, r);

    // M[r] = sum_{k,k'} Re( E_k conj(E_k') G[k,k'] )
    cplx E[16];
#pragma unroll
    for (int k = 0; k < 16; ++k) E[k] = rbuf[k][r];
    float M = 0.f;
#pragma unroll
    for (int k = 0; k < 16; ++k) {
#pragma unroll
        for (int k2 = 0; k2 < 16; ++k2) {
            cplx g = Gs[k * 16 + k2];
            float ar = fmaf(E[k].x, E[k2].x, E[k].y * E[k2].y);   // Re(E_k conj(E_k2))
            float ai = fmaf(E[k].y, E[k2].x, -E[k].x * E[k2].y);  // Im
            M = fmaf(ar, g.x, fmaf(-ai, g.y, M));
        }
    }
    // signs: post-perm index bits 17..14 = r bits 8..5
    float e0 = (r & 256) ? -M : M;
    float e1 = (r & 128) ? -M : M;
    float e2 = (r & 64)  ? -M : M;
    float e3 = (r & 32)  ? -M : M;
#pragma unroll
    for (int off = 32; off >= 1; off >>= 1) {
        e0 += __shfl_xor(e0, off); e1 += __shfl_xor(e1, off);
        e2 += __shfl_xor(e2, off); e3 += __shfl_xor(e3, off);
    }
    const int lane = tid & 63, wv = tid >> 6;
    if (lane == 0) { red[wv][0] = e0; red[wv][1] = e1; red[wv][2] = e2; red[wv][3] = e3; }
    __syncthreads();
    if (tid < 4) {
        float tot = 0.f;
#pragma unroll
        for (int k = 0; k < 8; ++k) tot += red[k][tid];
        out[b * 4 + tid] = tot;
    }
}

// ------------------------------------------------------------- launch -------
extern "C" void kernel_launch(void* const* d_in, const int* in_sizes, int n_in,
                              void* d_out, int out_size, void* d_ws, size_t ws_size,
                              hipStream_t stream) {
    const float* w = (const float*)d_in[0];   // (4,18,3) f32
    const int* x = (const int*)d_in[1];       // (64,9) i32
    float* out = (float*)d_out;               // (64,4) f32
    (void)d_ws; (void)ws_size; (void)n_in; (void)in_sizes; (void)out_size;

    k_prep<<<1, 512, 0, stream>>>(w);
    k_row<<<64, 512, 0, stream>>>(x, out);
}

// Round 9
// 82.955 us; speedup vs baseline: 6.3587x; 1.3801x over previous
//
#include <hip/hip_runtime.h>

// VQC: 18 qubits, 4 layers, batch 64 — FACTORIZED, single fused kernel.
// Across the row/col cut (index bits 9..17 | 0..8) only one CNOT per layer
// crosses the cut (the g_8 = o_8 ^ o_9 term of the Gray perm o -> o^(o>>1)),
// so the state is always  sum_k E_k[row] * C_k[col]  with rank doubling at
// each of the first THREE permutations: 1->2->4->8. The 4th (final) perm is
// followed only by measurement -> folded into signs (prefix parity of row
// bits 8..5; verified in the full-state kernels of rounds 3-6).
//   perm: E'_{2k+q}[R] = (R&1==q) ? E_k[R^(R>>1)] : 0
//         C'_{2k+q}[C] = C_k[(C^(C>>1)) ^ (q<<8)]
// Measurement: ev_i(b) = sum_R s_i[R] * M[R],
//   M[R] = sum_{k,k'} Re( E_k[R] conj(E_k'[R]) G[k,k'] ),  G = col Gram 8x8.
// One block per batch (64 blocks, 512 thr). Thread owns element idx of every
// rank vector in REGISTERS; gates on bits 0..5 use shfl (no barriers), bits
// 6..8 one batched LDS round-trip, perms one batched LDS gather. Col pipeline
// + Gram computed redundantly per block (parallel, batch-independent).

#define NQ 18

using cplx = float2;

__device__ __forceinline__ cplx cmul(cplx a, cplx b) {
    return make_float2(a.x * b.x - a.y * b.y, a.x * b.y + a.y * b.x);
}
// a*o0 + b*o1 (complex)
__device__ __forceinline__ cplx cfma2(cplx a, cplx o0, cplx b, cplx o1) {
    float re = fmaf(a.x, o0.x, fmaf(-a.y, o0.y, fmaf(b.x, o1.x, -b.y * o1.y)));
    float im = fmaf(a.x, o0.y, fmaf(a.y, o0.x, fmaf(b.x, o1.y, b.y * o1.x)));
    return make_float2(re, im);
}

// Layer-l gates on K register-resident vectors. Bit bpos pairs idx, idx^2^bpos:
// bpos 0..5 intra-wave (shfl, no barrier), 6..8 cross-wave (batched LDS, 2 bar).
// qubit = QOF - bpos (row side QOF=8, col side QOF=17).
template <int K, int QOF>
__device__ __forceinline__ void gates_layer(cplx* E, const cplx* Us, int l,
                                            int idx, cplx (*s)[512]) {
#pragma unroll
    for (int bpos = 0; bpos < 6; ++bpos) {
        const int m = 1 << bpos;
        const int bit = (idx >> bpos) & 1;
        const cplx* U = &Us[(l * NQ + (QOF - bpos)) * 4];
        const cplx ua = bit ? U[3] : U[0];   // U[bit][bit]
        const cplx ub = bit ? U[2] : U[1];   // U[bit][bit^1]
#pragma unroll
        for (int k = 0; k < K; ++k) {
            cplx p;
            p.x = __shfl_xor(E[k].x, m);
            p.y = __shfl_xor(E[k].y, m);
            E[k] = cfma2(ua, E[k], ub, p);
        }
    }
#pragma unroll
    for (int bpos = 6; bpos < 9; ++bpos) {
        const int m = 1 << bpos;
        const int bit = (idx >> bpos) & 1;
        const cplx* U = &Us[(l * NQ + (QOF - bpos)) * 4];
        const cplx ua = bit ? U[3] : U[0];
        const cplx ub = bit ? U[2] : U[1];
#pragma unroll
        for (int k = 0; k < K; ++k) s[k][idx] = E[k];
        __syncthreads();
        cplx p[K];
#pragma unroll
        for (int k = 0; k < K; ++k) p[k] = s[k][idx ^ m];
        __syncthreads();
#pragma unroll
        for (int k = 0; k < K; ++k) E[k] = cfma2(ua, E[k], ub, p[k]);
    }
}

// Gray perm + rank split K -> 2K, register-resident, one batched LDS gather.
template <int K, int ROW>
__device__ __forceinline__ void perm_split(cplx* E, int idx, cplx (*s)[512]) {
    const int gi = idx ^ (idx >> 1);
#pragma unroll
    for (int k = 0; k < K; ++k) s[k][idx] = E[k];
    __syncthreads();
    cplx v0[K], v1[K];
#pragma unroll
    for (int k = 0; k < K; ++k) {
        if (ROW) {
            cplx v = s[k][gi];
            v0[k] = (idx & 1) ? make_float2(0.f, 0.f) : v;
            v1[k] = (idx & 1) ? v : make_float2(0.f, 0.f);
        } else {
            v0[k] = s[k][gi];
            v1[k] = s[k][gi ^ 256];
        }
    }
    __syncthreads();
#pragma unroll
    for (int k = K - 1; k >= 0; --k) { E[2 * k] = v0[k]; E[2 * k + 1] = v1[k]; }
}

__global__ __launch_bounds__(512) void k_vqc(const float* __restrict__ w,
                                             const int* __restrict__ x,
                                             float* __restrict__ out) {
    __shared__ cplx Us[4 * NQ * 4];
    __shared__ cplx s[8][512];   // 32 KiB scratch (col vecs, then row exchange)
    __shared__ cplx Gs[64];      // col Gram 8x8
    __shared__ float red[8][4];
    const int tid = threadIdx.x;
    const int b = blockIdx.x;

    if (tid < 4 * NQ) {
        float phi = w[tid * 3 + 0], th = w[tid * 3 + 1], om = w[tid * 3 + 2];
        float sn, cs, sa, ca, sb, cb;
        sincosf(0.5f * th, &sn, &cs);
        sincosf(-0.5f * (phi + om), &sa, &ca);   // a = exp(-i(phi+om)/2)
        sincosf(0.5f * (phi - om), &sb, &cb);    // b = exp(+i(phi-om)/2)
        Us[tid * 4 + 0] = make_float2(ca * cs, sa * cs);    // U00 = a*c
        Us[tid * 4 + 1] = make_float2(-cb * sn, -sb * sn);  // U01 = -b*s
        Us[tid * 4 + 2] = make_float2(cb * sn, -sb * sn);   // U10 = conj(b)*s
        Us[tid * 4 + 3] = make_float2(ca * cs, -sa * cs);   // U11 = conj(a)*c
    }
    __syncthreads();

    cplx E[8];

    // ---------------- col pipeline (batch-independent) ----------------
    {   // layer-0 low gates on basis col 0: product form
        cplx B = make_float2(1.f, 0.f);
#pragma unroll
        for (int j = 0; j < 9; ++j) {
            int bit = (tid >> (8 - j)) & 1;             // qubit 9+j = col bit 8-j
            B = cmul(B, Us[(9 + j) * 4 + bit * 2 + 0]); // input bit 0
        }
        E[0] = B;
    }
    perm_split<1, 0>(E, tid, s);
    gates_layer<2, 17>(E, Us, 1, tid, s);
    perm_split<2, 0>(E, tid, s);
    gates_layer<4, 17>(E, Us, 2, tid, s);
    perm_split<4, 0>(E, tid, s);
    gates_layer<8, 17>(E, Us, 3, tid, s);
    // (no 4th perm: folded into measurement signs)

#pragma unroll
    for (int k = 0; k < 8; ++k) s[k][tid] = E[k];
    __syncthreads();
    {   // Gram: 64 entries x 8 threads each (sub-reduce via shfl in 8-lane groups)
        const int e = tid >> 3, sub = tid & 7;
        const int k = e >> 3, k2 = e & 7;
        float gr = 0.f, gi = 0.f;
        const int c0 = sub * 64;
        for (int c = c0; c < c0 + 64; ++c) {
            cplx a = s[k][c], bb = s[k2][c];
            gr = fmaf(a.x, bb.x, fmaf(a.y, bb.y, gr));
            gi = fmaf(a.y, bb.x, fmaf(-a.x, bb.y, gi));
        }
#pragma unroll
        for (int mm = 1; mm < 8; mm <<= 1) {
            gr += __shfl_xor(gr, mm);
            gi += __shfl_xor(gi, mm);
        }
        if (sub == 0) Gs[e] = make_float2(gr, gi);
    }
    __syncthreads();   // Gram reads done; s reusable, Gs visible

    // ---------------- row pipeline (this batch) ----------------
    {   // layer-0 high gates on basis row (closed form from x_b)
        cplx A = make_float2(1.f, 0.f);
#pragma unroll
        for (int j = 0; j < 9; ++j) {
            int bit = (tid >> (8 - j)) & 1;   // qubit j = row bit 8-j
            int xb = x[b * 9 + j];
            A = cmul(A, Us[j * 4 + bit * 2 + xb]);
        }
        E[0] = A;
    }
    perm_split<1, 1>(E, tid, s);
    gates_layer<2, 8>(E, Us, 1, tid, s);
    perm_split<2, 1>(E, tid, s);
    gates_layer<4, 8>(E, Us, 2, tid, s);
    perm_split<4, 1>(E, tid, s);
    gates_layer<8, 8>(E, Us, 3, tid, s);

    // ---------------- measurement ----------------
    float M = 0.f;
#pragma unroll
    for (int k = 0; k < 8; ++k) {
#pragma unroll
        for (int k2 = 0; k2 < 8; ++k2) {
            cplx g = Gs[k * 8 + k2];
            float ar = fmaf(E[k].x, E[k2].x, E[k].y * E[k2].y);   // Re(E_k conj(E_k2))
            float ai = fmaf(E[k].y, E[k2].x, -E[k].x * E[k2].y);  // Im
            M = fmaf(ar, g.x, fmaf(-ai, g.y, M));
        }
    }
    // signs: o = invGray(m), m bits 17..14 = r bits 8..5 -> prefix parities
    const int r = tid;
    const int p8 = (r >> 8) & 1;
    const int p7 = p8 ^ ((r >> 7) & 1);
    const int p6 = p7 ^ ((r >> 6) & 1);
    const int p5 = p6 ^ ((r >> 5) & 1);
    float e0 = p8 ? -M : M, e1 = p7 ? -M : M;
    float e2 = p6 ? -M : M, e3 = p5 ? -M : M;
#pragma unroll
    for (int off = 32; off >= 1; off >>= 1) {
        e0 += __shfl_xor(e0, off); e1 += __shfl_xor(e1, off);
        e2 += __shfl_xor(e2, off); e3 += __shfl_xor(e3, off);
    }
    const int lane = tid & 63, wv = tid >> 6;
    if (lane == 0) { red[wv][0] = e0; red[wv][1] = e1; red[wv][2] = e2; red[wv][3] = e3; }
    __syncthreads();
    if (tid < 4) {
        float tot = 0.f;
#pragma unroll
        for (int k = 0; k < 8; ++k) tot += red[k][tid];
        out[b * 4 + tid] = tot;
    }
}

// ------------------------------------------------------------- launch -------
extern "C" void kernel_launch(void* const* d_in, const int* in_sizes, int n_in,
                              void* d_out, int out_size, void* d_ws, size_t ws_size,
                              hipStream_t stream) {
    const float* w = (const float*)d_in[0];   // (4,18,3) f32
    const int* x = (const int*)d_in[1];       // (64,9) i32
    float* out = (float*)d_out;               // (64,4) f32
    (void)d_ws; (void)ws_size; (void)n_in; (void)in_sizes; (void)out_size;

    k_vqc<<<64, 512, 0, stream>>>(w, x, out);
}

// Round 10
// 77.625 us; speedup vs baseline: 6.7953x; 1.0687x over previous
//
#include <hip/hip_runtime.h>

// VQC: 18 qubits, 4 layers, batch 64 — FACTORIZED, single fused kernel, R10.
// Factorization (verified passing R7-R9): across the row/col cut (index bits
// 9..17 | 0..8) only one CNOT/layer crosses, so state = sum_k E_k[row]*C_k[col]
// with rank 1->2->4->8 over the first three Gray perms; the 4th perm is folded
// into measurement signs (prefix parity of row bits 8..5).
// R10 layout: thread = (rank wave, lane t), 8 slots/thread (idx = e*64 + t).
//   gates bits 0..5 = shfl_xor, bits 6..8 = register pairs -> ZERO barriers/LDS
//   for all gates. Only the 3 perms use LDS (2 barriers each).
//   Waves 0-7 = col ranks, 8-15 = row ranks -> col & row pipelines CONCURRENT.
//   Inactive ranks carry zeros (zero-propagation through linear ops).
// Perm gather in split layout: src slot = (gray3(e)^(q<<2))*64
//   + ((t^(t>>1)) ^ ((e&1)<<5));  row side: no e-flip, mask (t&1)==q.
// LDS rows padded to 516 cplx -> Gram/meas/perm accesses <=2-way (free).
//   ev_i(b) = sum_r sign_i(r) * sum_{k,k'} Re(E_k[r] conj(E_k'[r]) G[k,k']).

#define NQ 18

using cplx = float2;

__device__ __forceinline__ cplx cmul(cplx a, cplx b) {
    return make_float2(a.x * b.x - a.y * b.y, a.x * b.y + a.y * b.x);
}
// a*o0 + b*o1 (complex)
__device__ __forceinline__ cplx cfma2(cplx a, cplx o0, cplx b, cplx o1) {
    float re = fmaf(a.x, o0.x, fmaf(-a.y, o0.y, fmaf(b.x, o1.x, -b.y * o1.y)));
    float im = fmaf(a.x, o0.y, fmaf(a.y, o0.x, fmaf(b.x, o1.y, b.y * o1.x)));
    return make_float2(re, im);
}

__global__ __launch_bounds__(1024) void k_vqc(const float* __restrict__ w,
                                              const int* __restrict__ x,
                                              float* __restrict__ out) {
    __shared__ cplx Us[4 * NQ * 4];
    __shared__ cplx sc[8][516];   // col ranks (padded: 2*516 mod 32 = 8)
    __shared__ cplx sr[8][516];   // row ranks
    __shared__ cplx Gs[64];
    __shared__ float red[8][4];
    __shared__ int xb[9];
    const int tid = threadIdx.x;
    const int b = blockIdx.x;
    const int t = tid & 63;       // lane
    const int wv = tid >> 6;      // 0..15
    const int isrow = wv >> 3;    // 0 = col pipeline, 1 = row pipeline
    const int rk = wv & 7;        // rank within side
    cplx (*sb)[516] = isrow ? sr : sc;
    const int qof = isrow ? 8 : 17;   // qubit = qof - bitpos

    if (tid < 9) xb[tid] = x[b * 9 + tid];
    if (tid < 4 * NQ) {
        float phi = w[tid * 3 + 0], th = w[tid * 3 + 1], om = w[tid * 3 + 2];
        float sn, cs, sa, ca, sb2, cb;
        sincosf(0.5f * th, &sn, &cs);
        sincosf(-0.5f * (phi + om), &sa, &ca);   // a = exp(-i(phi+om)/2)
        sincosf(0.5f * (phi - om), &sb2, &cb);   // b = exp(+i(phi-om)/2)
        Us[tid * 4 + 0] = make_float2(ca * cs, sa * cs);     // U00 = a*c
        Us[tid * 4 + 1] = make_float2(-cb * sn, -sb2 * sn);  // U01 = -b*s
        Us[tid * 4 + 2] = make_float2(cb * sn, -sb2 * sn);   // U10 = conj(b)*s
        Us[tid * 4 + 3] = make_float2(ca * cs, -sa * cs);    // U11 = conj(a)*c
    }
    __syncthreads();

    cplx E[8];
#pragma unroll
    for (int e = 0; e < 8; ++e) E[e] = make_float2(0.f, 0.f);

    // -------- layer-0 init (rank 0 of each side; others stay zero) --------
    if (wv == 0) {            // col: basis col 0 -> product form
#pragma unroll
        for (int e = 0; e < 8; ++e) {
            const int idx = e * 64 + t;
            cplx B = make_float2(1.f, 0.f);
#pragma unroll
            for (int j = 0; j < 9; ++j) {
                int bit = (idx >> (8 - j)) & 1;             // qubit 9+j
                B = cmul(B, Us[(9 + j) * 4 + bit * 2 + 0]);
            }
            E[e] = B;
        }
    } else if (wv == 8) {     // row: basis row from x_b
#pragma unroll
        for (int e = 0; e < 8; ++e) {
            const int idx = e * 64 + t;
            cplx A = make_float2(1.f, 0.f);
#pragma unroll
            for (int j = 0; j < 9; ++j) {
                int bit = (idx >> (8 - j)) & 1;             // qubit j
                A = cmul(A, Us[j * 4 + bit * 2 + xb[j]]);
            }
            E[e] = A;
        }
    }

    const int srck = rk >> 1, q = rk & 1;
    const int tg = t ^ (t >> 1);
    const int eflip = isrow ? 0 : (q << 2);
    const int keepmask = isrow ? ((t & 1) == q) : 1;

    // Gray perm + rank split (store all ranks, gather from rank rk>>1)
#define PERM()                                                              \
    {                                                                       \
        _Pragma("unroll") for (int e = 0; e < 8; ++e)                       \
            sb[rk][e * 64 + t] = E[e];                                      \
        __syncthreads();                                                    \
        cplx V[8];                                                          \
        _Pragma("unroll") for (int e = 0; e < 8; ++e) {                     \
            const int slot =                                                \
                (((e ^ (e >> 1)) ^ eflip) << 6) | (tg ^ ((e & 1) << 5));    \
            cplx v = sb[srck][slot];                                        \
            if (!keepmask) v = make_float2(0.f, 0.f);                       \
            V[e] = v;                                                       \
        }                                                                   \
        __syncthreads();                                                    \
        _Pragma("unroll") for (int e = 0; e < 8; ++e) E[e] = V[e];          \
    }

    // 9 gates of layer l: bits 0..5 shfl, bits 6..8 register pairs. No LDS.
#define GATES(l)                                                            \
    {                                                                       \
        _Pragma("unroll") for (int bp = 0; bp < 6; ++bp) {                  \
            const int m = 1 << bp;                                          \
            const cplx* U = &Us[((l) * NQ + (qof - bp)) * 4];               \
            const int bit = (t >> bp) & 1;                                  \
            const cplx ua = bit ? U[3] : U[0];                              \
            const cplx ub = bit ? U[2] : U[1];                              \
            _Pragma("unroll") for (int e = 0; e < 8; ++e) {                 \
                cplx p;                                                     \
                p.x = __shfl_xor(E[e].x, m);                                \
                p.y = __shfl_xor(E[e].y, m);                                \
                E[e] = cfma2(ua, E[e], ub, p);                              \
            }                                                               \
        }                                                                   \
        _Pragma("unroll") for (int bb = 0; bb < 3; ++bb) {                  \
            const cplx* U = &Us[((l) * NQ + (qof - 6 - bb)) * 4];           \
            const cplx u0 = U[0], u1 = U[1], u2 = U[2], u3 = U[3];          \
            const int st = 1 << bb;                                         \
            _Pragma("unroll") for (int e = 0; e < 8; ++e) if (!(e & st)) {  \
                cplx o0 = E[e], o1 = E[e | st];                             \
                E[e]      = cfma2(u0, o0, u1, o1);                          \
                E[e | st] = cfma2(u2, o0, u3, o1);                          \
            }                                                               \
        }                                                                   \
    }

    PERM(); GATES(1);
    PERM(); GATES(2);
    PERM(); GATES(3);
    // (4th perm folded into measurement signs)

#pragma unroll
    for (int e = 0; e < 8; ++e) sb[rk][e * 64 + t] = E[e];
    __syncthreads();

    // -------- col Gram: G[k,k2] = sum_C C_k[C] conj(C_k2[C]) --------
    if (tid < 512) {
        const int ee = tid >> 3, sub = tid & 7;
        const int k = ee >> 3, k2 = ee & 7;
        float gr = 0.f, gi = 0.f;
#pragma unroll
        for (int i = 0; i < 64; ++i) {
            const int c = sub + 8 * i;      // a: 8-addr broadcast; bb: 2-way
            cplx a = sc[k][c], bb2 = sc[k2][c];
            gr = fmaf(a.x, bb2.x, fmaf(a.y, bb2.y, gr));
            gi = fmaf(a.y, bb2.x, fmaf(-a.x, bb2.y, gi));
        }
#pragma unroll
        for (int mm = 1; mm < 8; mm <<= 1) {
            gr += __shfl_xor(gr, mm);
            gi += __shfl_xor(gi, mm);
        }
        if (sub == 0) Gs[ee] = make_float2(gr, gi);
    }
    __syncthreads();

    // -------- measurement --------
    if (tid < 512) {
        const int r = tid;
        cplx Ek[8];
#pragma unroll
        for (int k = 0; k < 8; ++k) Ek[k] = sr[k][r];
        float M = 0.f;
#pragma unroll
        for (int k = 0; k < 8; ++k) {
#pragma unroll
            for (int k2 = 0; k2 < 8; ++k2) {
                cplx g = Gs[k * 8 + k2];
                float ar = fmaf(Ek[k].x, Ek[k2].x, Ek[k].y * Ek[k2].y);
                float ai = fmaf(Ek[k].y, Ek[k2].x, -Ek[k].x * Ek[k2].y);
                M = fmaf(ar, g.x, fmaf(-ai, g.y, M));
            }
        }
        // signs: prefix parities of r bits 8..5 (verified R3-R9)
        const int p8 = (r >> 8) & 1;
        const int p7 = p8 ^ ((r >> 7) & 1);
        const int p6 = p7 ^ ((r >> 6) & 1);
        const int p5 = p6 ^ ((r >> 5) & 1);
        float e0 = p8 ? -M : M, e1 = p7 ? -M : M;
        float e2 = p6 ? -M : M, e3 = p5 ? -M : M;
#pragma unroll
        for (int off = 32; off >= 1; off >>= 1) {
            e0 += __shfl_xor(e0, off); e1 += __shfl_xor(e1, off);
            e2 += __shfl_xor(e2, off); e3 += __shfl_xor(e3, off);
        }
        if (t == 0) {
            red[wv][0] = e0; red[wv][1] = e1;
            red[wv][2] = e2; red[wv][3] = e3;
        }
    }
    __syncthreads();
    if (tid < 4) {
        float tot = 0.f;
#pragma unroll
        for (int k = 0; k < 8; ++k) tot += red[k][tid];
        out[b * 4 + tid] = tot;
    }
}

// ------------------------------------------------------------- launch -------
extern "C" void kernel_launch(void* const* d_in, const int* in_sizes, int n_in,
                              void* d_out, int out_size, void* d_ws, size_t ws_size,
                              hipStream_t stream) {
    const float* w = (const float*)d_in[0];   // (4,18,3) f32
    const int* x = (const int*)d_in[1];       // (64,9) i32
    float* out = (float*)d_out;               // (64,4) f32
    (void)d_ws; (void)ws_size; (void)n_in; (void)in_sizes; (void)out_size;

    k_vqc<<<64, 1024, 0, stream>>>(w, x, out);
}

// Round 11
// 76.816 us; speedup vs baseline: 6.8669x; 1.0105x over previous
//
#include <hip/hip_runtime.h>

// VQC: 18 qubits, 4 layers, batch 64 — FACTORIZED, single fused kernel, R11.
// Factorization (verified passing R7-R10): across the row/col cut (index bits
// 9..17 | 0..8) only one CNOT/layer crosses, so state = sum_k E_k[row]*C_k[col]
// with rank 1->2->4->8 over the first three Gray perms; the 4th perm is folded
// into measurement signs (prefix parity of row bits 8..5).
// Layout: thread = (rank wave, lane t), 8 slots/thread (idx = e*64 + t).
//   gates bits 0..5 = shfl_xor, bits 6..8 = register pairs -> no LDS/barriers
//   for gates. Waves 0-7 = col ranks, 8-15 = row ranks (concurrent pipelines).
// R11: ping-pong LDS perm buffers -> ONE barrier per perm (write p, sync,
//   gather p; next perm uses p^1 — reuse separated by the next perm's barrier).
//   Gram uses all 1024 threads. Barriers 10 -> 7.
// Perm gather in split layout (re-derived bit-by-bit):
//   slot = ((gray3(e)^ (q<<2 col)) << 6) | ((t^(t>>1)) ^ ((e&1)<<5));
//   row side: no e-flip, keep iff (t&1)==q.
//   ev_i(b) = sum_r sign_i(r) * sum_{k,k'} Re(E_k[r] conj(E_k'[r]) G[k,k']).

#define NQ 18

using cplx = float2;

__device__ __forceinline__ cplx cmul(cplx a, cplx b) {
    return make_float2(a.x * b.x - a.y * b.y, a.x * b.y + a.y * b.x);
}
// a*o0 + b*o1 (complex)
__device__ __forceinline__ cplx cfma2(cplx a, cplx o0, cplx b, cplx o1) {
    float re = fmaf(a.x, o0.x, fmaf(-a.y, o0.y, fmaf(b.x, o1.x, -b.y * o1.y)));
    float im = fmaf(a.x, o0.y, fmaf(a.y, o0.x, fmaf(b.x, o1.y, b.y * o1.x)));
    return make_float2(re, im);
}

__global__ __launch_bounds__(1024) void k_vqc(const float* __restrict__ w,
                                              const int* __restrict__ x,
                                              float* __restrict__ out) {
    __shared__ cplx Us[4 * NQ * 4];
    __shared__ cplx sb[2][2][8][516];   // [pingpong][side][rank][elem] 132 KiB
    __shared__ cplx Gs[64];
    __shared__ float red[8][4];
    __shared__ int xb[9];
    const int tid = threadIdx.x;
    const int b = blockIdx.x;
    const int t = tid & 63;       // lane
    const int wv = tid >> 6;      // 0..15
    const int side = wv >> 3;     // 0 = col pipeline, 1 = row pipeline
    const int rk = wv & 7;        // rank within side
    const int qof = side ? 8 : 17;   // qubit = qof - bitpos

    if (tid < 9) xb[tid] = x[b * 9 + tid];
    if (tid < 4 * NQ) {
        float phi = w[tid * 3 + 0], th = w[tid * 3 + 1], om = w[tid * 3 + 2];
        float sn, cs, sa, ca, sb2, cb;
        sincosf(0.5f * th, &sn, &cs);
        sincosf(-0.5f * (phi + om), &sa, &ca);   // a = exp(-i(phi+om)/2)
        sincosf(0.5f * (phi - om), &sb2, &cb);   // b = exp(+i(phi-om)/2)
        Us[tid * 4 + 0] = make_float2(ca * cs, sa * cs);     // U00 = a*c
        Us[tid * 4 + 1] = make_float2(-cb * sn, -sb2 * sn);  // U01 = -b*s
        Us[tid * 4 + 2] = make_float2(cb * sn, -sb2 * sn);   // U10 = conj(b)*s
        Us[tid * 4 + 3] = make_float2(ca * cs, -sa * cs);    // U11 = conj(a)*c
    }
    __syncthreads();   // barrier 1

    cplx E[8];
#pragma unroll
    for (int e = 0; e < 8; ++e) E[e] = make_float2(0.f, 0.f);

    // -------- layer-0 init (rank 0 of each side; others stay zero) --------
    if (wv == 0) {            // col: basis col 0 -> product form
#pragma unroll
        for (int e = 0; e < 8; ++e) {
            const int idx = e * 64 + t;
            cplx B = make_float2(1.f, 0.f);
#pragma unroll
            for (int j = 0; j < 9; ++j) {
                int bit = (idx >> (8 - j)) & 1;             // qubit 9+j
                B = cmul(B, Us[(9 + j) * 4 + bit * 2 + 0]);
            }
            E[e] = B;
        }
    } else if (wv == 8) {     // row: basis row from x_b
#pragma unroll
        for (int e = 0; e < 8; ++e) {
            const int idx = e * 64 + t;
            cplx A = make_float2(1.f, 0.f);
#pragma unroll
            for (int j = 0; j < 9; ++j) {
                int bit = (idx >> (8 - j)) & 1;             // qubit j
                A = cmul(A, Us[j * 4 + bit * 2 + xb[j]]);
            }
            E[e] = A;
        }
    }

    const int srck = rk >> 1, q = rk & 1;
    const int tg = t ^ (t >> 1);
    const int eflip = side ? 0 : (q << 2);
    const int keepmask = side ? ((t & 1) == q) : 1;

    // Gray perm + rank split; ONE barrier (ping-pong buffer p).
    // Reuse of buffer p^1 is separated from its prior readers by this barrier.
#define PERM(p)                                                             \
    {                                                                       \
        _Pragma("unroll") for (int e = 0; e < 8; ++e)                       \
            sb[p][side][rk][e * 64 + t] = E[e];                             \
        __syncthreads();                                                    \
        _Pragma("unroll") for (int e = 0; e < 8; ++e) {                     \
            const int slot =                                                \
                (((e ^ (e >> 1)) ^ eflip) << 6) | (tg ^ ((e & 1) << 5));    \
            cplx v = sb[p][side][srck][slot];                               \
            if (!keepmask) v = make_float2(0.f, 0.f);                       \
            E[e] = v;                                                       \
        }                                                                   \
    }

    // 9 gates of layer l: bits 0..5 shfl, bits 6..8 register pairs. No LDS.
#define GATES(l)                                                            \
    {                                                                       \
        _Pragma("unroll") for (int bp = 0; bp < 6; ++bp) {                  \
            const int m = 1 << bp;                                          \
            const cplx* U = &Us[((l) * NQ + (qof - bp)) * 4];               \
            const int bit = (t >> bp) & 1;                                  \
            const cplx ua = bit ? U[3] : U[0];                              \
            const cplx ub = bit ? U[2] : U[1];                              \
            _Pragma("unroll") for (int e = 0; e < 8; ++e) {                 \
                cplx p2;                                                    \
                p2.x = __shfl_xor(E[e].x, m);                               \
                p2.y = __shfl_xor(E[e].y, m);                               \
                E[e] = cfma2(ua, E[e], ub, p2);                             \
            }                                                               \
        }                                                                   \
        _Pragma("unroll") for (int bb = 0; bb < 3; ++bb) {                  \
            const cplx* U = &Us[((l) * NQ + (qof - 6 - bb)) * 4];           \
            const cplx u0 = U[0], u1 = U[1], u2 = U[2], u3 = U[3];          \
            const int st = 1 << bb;                                         \
            _Pragma("unroll") for (int e = 0; e < 8; ++e) if (!(e & st)) {  \
                cplx o0 = E[e], o1 = E[e | st];                             \
                E[e]      = cfma2(u0, o0, u1, o1);                          \
                E[e | st] = cfma2(u2, o0, u3, o1);                          \
            }                                                               \
        }                                                                   \
    }

    PERM(0); GATES(1);   // barrier 2
    PERM(1); GATES(2);   // barrier 3
    PERM(0); GATES(3);   // barrier 4
    // (4th perm folded into measurement signs)

    // final store -> buffer 1 (its last readers finished before barrier 4)
#pragma unroll
    for (int e = 0; e < 8; ++e) sb[1][side][rk][e * 64 + t] = E[e];
    __syncthreads();   // barrier 5

    // -------- col Gram: G[k,k2] = sum_C C_k[C] conj(C_k2[C]); all 1024 thr --
    {
        const int ee = tid >> 4, sub = tid & 15;
        const int k = ee >> 3, k2 = ee & 7;
        float gr = 0.f, gi = 0.f;
#pragma unroll
        for (int i = 0; i < 32; ++i) {
            const int c = sub + 16 * i;
            cplx a = sb[1][0][k][c], bb2 = sb[1][0][k2][c];
            gr = fmaf(a.x, bb2.x, fmaf(a.y, bb2.y, gr));
            gi = fmaf(a.y, bb2.x, fmaf(-a.x, bb2.y, gi));
        }
#pragma unroll
        for (int mm = 1; mm < 16; mm <<= 1) {
            gr += __shfl_xor(gr, mm);
            gi += __shfl_xor(gi, mm);
        }
        if (sub == 0) Gs[ee] = make_float2(gr, gi);
    }
    __syncthreads();   // barrier 6

    // -------- measurement --------
    if (tid < 512) {
        const int r = tid;
        cplx Ek[8];
#pragma unroll
        for (int k = 0; k < 8; ++k) Ek[k] = sb[1][1][k][r];
        float M = 0.f;
#pragma unroll
        for (int k = 0; k < 8; ++k) {
#pragma unroll
            for (int k2 = 0; k2 < 8; ++k2) {
                cplx g = Gs[k * 8 + k2];
                float ar = fmaf(Ek[k].x, Ek[k2].x, Ek[k].y * Ek[k2].y);
                float ai = fmaf(Ek[k].y, Ek[k2].x, -Ek[k].x * Ek[k2].y);
                M = fmaf(ar, g.x, fmaf(-ai, g.y, M));
            }
        }
        // signs: prefix parities of r bits 8..5 (verified R3-R10)
        const int p8 = (r >> 8) & 1;
        const int p7 = p8 ^ ((r >> 7) & 1);
        const int p6 = p7 ^ ((r >> 6) & 1);
        const int p5 = p6 ^ ((r >> 5) & 1);
        float e0 = p8 ? -M : M, e1 = p7 ? -M : M;
        float e2 = p6 ? -M : M, e3 = p5 ? -M : M;
#pragma unroll
        for (int off = 32; off >= 1; off >>= 1) {
            e0 += __shfl_xor(e0, off); e1 += __shfl_xor(e1, off);
            e2 += __shfl_xor(e2, off); e3 += __shfl_xor(e3, off);
        }
        if (t == 0) {
            red[wv][0] = e0; red[wv][1] = e1;
            red[wv][2] = e2; red[wv][3] = e3;
        }
    }
    __syncthreads();   // barrier 7
    if (tid < 4) {
        float tot = 0.f;
#pragma unroll
        for (int k = 0; k < 8; ++k) tot += red[k][tid];
        out[b * 4 + tid] = tot;
    }
}

// ------------------------------------------------------------- launch -------
extern "C" void kernel_launch(void* const* d_in, const int* in_sizes, int n_in,
                              void* d_out, int out_size, void* d_ws, size_t ws_size,
                              hipStream_t stream) {
    const float* w = (const float*)d_in[0];   // (4,18,3) f32
    const int* x = (const int*)d_in[1];       // (64,9) i32
    float* out = (float*)d_out;               // (64,4) f32
    (void)d_ws; (void)ws_size; (void)n_in; (void)in_sizes; (void)out_size;

    k_vqc<<<64, 1024, 0, stream>>>(w, x, out);
}